// Round 6
// baseline (569.053 us; speedup 1.0000x reference)
//
#include <hip/hip_runtime.h>
#include <math.h>

#define DEVFN __device__ __forceinline__

typedef __attribute__((ext_vector_type(4))) float f32x4;
typedef __attribute__((ext_vector_type(8))) __bf16 bf16x8;
typedef __attribute__((ext_vector_type(8))) short short8v;

#define NB   64
#define TXD  1024
#define NHD  512
#define HSZ  512
#define ESZ  300
#define VSZ  32000
#define G4   (4*HSZ)           // 2048
#define KPRE (ESZ + NHD + HSZ) // 1324 (emb|c_prev|h0)
#define KPOST 1536             // (h0out|ctx|h1)
#define HALFD 512

DEVFN short f2bf(float f) {
  unsigned u = __float_as_uint(f);
  u = (u + 0x7fffu + ((u >> 16) & 1u)) >> 16;
  return (short)u;
}
DEVFN float sigm(float x) { return 1.0f / (1.0f + __expf(-x)); }

DEVFN short8v pack8(float4 a, float4 b) {
  short8v v;
  v[0]=f2bf(a.x); v[1]=f2bf(a.y); v[2]=f2bf(a.z); v[3]=f2bf(a.w);
  v[4]=f2bf(b.x); v[5]=f2bf(b.y); v[6]=f2bf(b.z); v[7]=f2bf(b.w);
  return v;
}
DEVFN bf16x8 pack8f(float4 a, float4 b) {
  bf16x8 v;
  v[0]=(__bf16)a.x; v[1]=(__bf16)a.y; v[2]=(__bf16)a.z; v[3]=(__bf16)a.w;
  v[4]=(__bf16)b.x; v[5]=(__bf16)b.y; v[6]=(__bf16)b.z; v[7]=(__bf16)b.w;
  return v;
}
// async global->LDS, 16B per lane: dest = wave-uniform base + lane*16
DEVFN void gload16(const void* g, void* lds_base) {
  __builtin_amdgcn_global_load_lds(
      (const __attribute__((address_space(1))) unsigned int*)g,
      (__attribute__((address_space(3))) unsigned int*)lds_base, 16, 0, 0);
}

DEVFN float4 ldA4(const float* __restrict__ A, int lda, int row, int k, int Ka) {
  if (k >= Ka) { float4 z = {0.f,0.f,0.f,0.f}; return z; }
  return *(const float4*)(A + (size_t)row * lda + k);
}
DEVFN float4 ldB4(const float* __restrict__ B1, int ldb1, int split,
                  const float* __restrict__ B2, int ldb2, int row, int k, int Ka) {
  if (k >= Ka) { float4 z = {0.f,0.f,0.f,0.f}; return z; }
  if (k < split) return *(const float4*)(B1 + (size_t)row * ldb1 + k);
  return *(const float4*)(B2 + (size_t)row * ldb2 + (k - split));
}

// ---------- prep: W1->bf16 (0..127) | pre concat (128..459) | zero cnt (460) ----
__global__ __launch_bounds__(256)
void prep(const int* __restrict__ yt, const float* __restrict__ embW,
          const float* __restrict__ c_prev, const float* __restrict__ h0,
          const float* __restrict__ W1, unsigned short* __restrict__ W1b,
          float* __restrict__ cat, unsigned int* __restrict__ cnt)
{
  int b = blockIdx.x;
  if (b < 128) {
    int i = b * 256 + threadIdx.x;            // 0..32767, 8 elems each
    int c = i >> 6, kq = (i & 63) * 8;
    float4 a = *(const float4*)(W1 + (size_t)c * 1024 + kq);
    float4 bb = *(const float4*)(W1 + (size_t)c * 1024 + kq + 4);
    *(short8v*)(W1b + (size_t)c * 512 + kq) = pack8(a, bb);
  } else if (b < 460) {
    int i = (b - 128) * 256 + threadIdx.x;    // < 64*1324
    if (i >= NB * KPRE) return;
    int n = i / KPRE, c = i - n * KPRE;
    float v;
    if (c < ESZ)            v = embW[(size_t)yt[n] * ESZ + c];
    else if (c < ESZ + NHD) v = c_prev[(size_t)n * NHD + (c - ESZ)];
    else                    v = h0[(size_t)n * HSZ + (c - ESZ - NHD)];
    cat[i] = v;
  } else {
    #pragma unroll
    for (int j = 0; j < 4; ++j) cnt[threadIdx.x + j*256] = 0u;
  }
}

// ---------- generic MFMA GEMM, 128-col tiles: C[64 x N] = A[64 x K] B[N x K]^T --
// Kslice multiple of 32. Split-K partial at C + ks*64*ldc.
// EPI: 0 none, 3 relu(x+bias1), 4 relu(x+bias1) + BN scale/shift outputs.
template<int EPI>
__global__ __launch_bounds__(256)
void mfma_gemm128(const float* __restrict__ A, int lda, int Ka,
                  const float* __restrict__ B1, int ldb1, int split,
                  const float* __restrict__ B2, int ldb2,
                  const float* __restrict__ bias1,
                  float* __restrict__ C, int ldc, int Kslice,
                  const float* __restrict__ gamma, const float* __restrict__ beta,
                  float* __restrict__ bnsc, float* __restrict__ bnsh)
{
  __shared__ __align__(16) short As[64][40];
  __shared__ __align__(16) short Bs[128][40];
  const int tid = threadIdx.x;
  const int w = tid >> 6, lane = tid & 63;
  const int wr = w >> 1, wc = w & 1;
  const int cl = lane & 15, g = lane >> 4;
  const int n0 = blockIdx.x * 128;
  const int ks = blockIdx.y;
  const int kbeg = ks * Kslice;
  const int kend = min(kbeg + Kslice, Ka);
  C += (size_t)ks * 64 * ldc;

  const f32x4 fz = {0.f,0.f,0.f,0.f};
  f32x4 acc[2][4];
  #pragma unroll
  for (int i = 0; i < 2; ++i)
    #pragma unroll
    for (int j = 0; j < 4; ++j) acc[i][j] = fz;

  const int sr  = tid >> 2;        // 0..63
  const int skc = (tid & 3) * 8;   // 0,8,16,24

  float4 ra0, ra1, rb0[2], rb1[2];
  ra0 = ldA4(A, lda, sr, kbeg + skc, Ka);
  ra1 = ldA4(A, lda, sr, kbeg + skc + 4, Ka);
  #pragma unroll
  for (int it = 0; it < 2; ++it) {
    rb0[it] = ldB4(B1, ldb1, split, B2, ldb2, n0 + sr + it*64, kbeg + skc, Ka);
    rb1[it] = ldB4(B1, ldb1, split, B2, ldb2, n0 + sr + it*64, kbeg + skc + 4, Ka);
  }

  for (int k0 = kbeg; k0 < kend; k0 += 32) {
    __syncthreads();
    *(short8v*)&As[sr][skc] = pack8(ra0, ra1);
    #pragma unroll
    for (int it = 0; it < 2; ++it)
      *(short8v*)&Bs[sr + it*64][skc] = pack8(rb0[it], rb1[it]);
    __syncthreads();
    if (k0 + 32 < kend) {
      ra0 = ldA4(A, lda, sr, k0 + 32 + skc, Ka);
      ra1 = ldA4(A, lda, sr, k0 + 32 + skc + 4, Ka);
      #pragma unroll
      for (int it = 0; it < 2; ++it) {
        rb0[it] = ldB4(B1, ldb1, split, B2, ldb2, n0 + sr + it*64, k0 + 32 + skc, Ka);
        rb1[it] = ldB4(B1, ldb1, split, B2, ldb2, n0 + sr + it*64, k0 + 32 + skc + 4, Ka);
      }
    }
    bf16x8 af[2], bfr[4];
    #pragma unroll
    for (int mi = 0; mi < 2; ++mi)
      af[mi] = *(const bf16x8*)&As[wr*32 + mi*16 + cl][g * 8];
    #pragma unroll
    for (int ni = 0; ni < 4; ++ni)
      bfr[ni] = *(const bf16x8*)&Bs[wc*64 + ni*16 + cl][g * 8];
    #pragma unroll
    for (int mi = 0; mi < 2; ++mi)
      #pragma unroll
      for (int ni = 0; ni < 4; ++ni)
        acc[mi][ni] = __builtin_amdgcn_mfma_f32_16x16x32_bf16(af[mi], bfr[ni], acc[mi][ni], 0, 0, 0);
  }

  float s1[4] = {0.f,0.f,0.f,0.f}, s2[4] = {0.f,0.f,0.f,0.f};
  #pragma unroll
  for (int ni = 0; ni < 4; ++ni) {
    int nn = n0 + wc*64 + ni*16 + cl;
    float b = (EPI >= 3) ? bias1[nn] : 0.f;
    #pragma unroll
    for (int mi = 0; mi < 2; ++mi)
      #pragma unroll
      for (int r = 0; r < 4; ++r) {
        int m = wr*32 + mi*16 + g*4 + r;
        float v = acc[mi][ni][r];
        if (EPI >= 3) v = fmaxf(v + b, 0.f);
        C[(size_t)m * ldc + nn] = v;
        if (EPI == 4) { s1[ni] += v; s2[ni] = fmaf(v, v, s2[ni]); }
      }
  }
  if (EPI == 4) {
    // reduce over g (lanes 16,32): per (wr,wc,ni,cl) -> 32-row sums
    #pragma unroll
    for (int mm = 16; mm < 64; mm <<= 1)
      #pragma unroll
      for (int ni = 0; ni < 4; ++ni) {
        s1[ni] += __shfl_xor(s1[ni], mm, 64);
        s2[ni] += __shfl_xor(s2[ni], mm, 64);
      }
    float* red = (float*)As;   // [2][128][2] = 2KB, staging dead
    __syncthreads();
    if (g == 0) {
      #pragma unroll
      for (int ni = 0; ni < 4; ++ni) {
        int col = wc*64 + ni*16 + cl;
        red[(wr*128 + col)*2 + 0] = s1[ni];
        red[(wr*128 + col)*2 + 1] = s2[ni];
      }
    }
    __syncthreads();
    if (tid < 128) {
      int col = n0 + tid;
      float a1 = red[tid*2] + red[(128 + tid)*2];
      float a2 = red[tid*2 + 1] + red[(128 + tid)*2 + 1];
      float mean = a1 * (1.0f / NB);
      float var = a2 * (1.0f / NB) - mean * mean;
      float rr = rsqrtf(var + 1e-5f);
      float sc = gamma[col] * rr;
      bnsc[col] = sc;
      bnsh[col] = beta[col] - mean * sc;
    }
  }
}

// ---------- LSTM pointwise, summing np split-K gate partials --------------------
__global__ __launch_bounds__(256)
void lstm_point2(const float* __restrict__ gp, int np,
                 const float* __restrict__ bih, const float* __restrict__ bhh,
                 const float* __restrict__ c_old,
                 float* __restrict__ h_new, float* __restrict__ c_new)
{
  int i = blockIdx.x * 256 + threadIdx.x;   // < 64*512
  int n = i >> 9, k = i & 511;
  float g[4];
  #pragma unroll
  for (int j = 0; j < 4; ++j) {
    int idx = j * 512 + k;
    float s = bih[idx] + bhh[idx];
    for (int ks = 0; ks < np; ++ks)
      s += gp[((size_t)ks*64 + n) * G4 + idx];
    g[j] = s;
  }
  float c = sigm(g[1]) * c_old[i] + sigm(g[0]) * tanhf(g[2]);
  float h = sigm(g[3]) * tanhf(c);
  h_new[i] = h; c_new[i] = c;
}

// ---------- fused attention v3: 64 rows x 256 cols per block, 4 waves -----------
// grid 2048 = 1024 row-tiles x 2 col-halves (bid = rt*2 + ch).
// A: enc f32 [64][32] LDS, slot16 ^= (row&3) both sides; bf16 at frag build.
// B: W1b bf16 [256][32] LDS, linear (64B rows are bank-uniform).
// Pair-combine: atomic counter; finisher does softmax + 64-row context pass.
__global__ __launch_bounds__(256, 4)
void att_fused2(const float* __restrict__ enc, const unsigned short* __restrict__ W1b,
                const float* __restrict__ W2, const float* __restrict__ sprojp,
                const float* __restrict__ b1,
                float* __restrict__ spart, float* __restrict__ mbuf,
                float* __restrict__ sbuf, float* __restrict__ ctxp,
                unsigned int* __restrict__ cnt)
{
  __shared__ __align__(16) char smem[49152];   // 2 x (A 8KB + B 16KB)
  __shared__ unsigned oldLds;
  const int tid = threadIdx.x;
  const int wid = tid >> 6, lane = tid & 63;
  const int cl = lane & 15, g = lane >> 4;
  const int rt = blockIdx.x >> 1, ch = blockIdx.x & 1;
  const int r0 = rt << 6, c0 = ch << 8;
  const int n = rt >> 4;

  // staging lane->src offsets
  const int a_r = lane >> 3;                         // 0..7 (128B rows, 8/gload)
  const int a_cf = (((lane & 7) ^ (a_r & 3)) << 2);  // f32 units (swizzled source)
  const int b_r = lane >> 2;                         // 0..15 (64B rows, 16/gload)
  const int b_ce = (lane & 3) << 3;                  // bf16 units

  const f32x4 fz = {0.f,0.f,0.f,0.f};
  f32x4 acc[4][4];
  #pragma unroll
  for (int mi = 0; mi < 4; ++mi)
    #pragma unroll
    for (int ni = 0; ni < 4; ++ni) acc[mi][ni] = fz;

  #define STAGE(s, t) do {                                                  \
    int k0 = (t) * 32;                                                      \
    _Pragma("unroll")                                                       \
    for (int jj = 0; jj < 2; ++jj) {                                        \
      int j = (wid << 1) + jj;                                              \
      gload16(enc + (size_t)(r0 + (j << 3) + a_r) * 512 + k0 + a_cf,        \
              smem + (s) * 24576 + (j << 10));                              \
    }                                                                       \
    _Pragma("unroll")                                                       \
    for (int jj = 0; jj < 4; ++jj) {                                        \
      int j = (wid << 2) + jj;                                              \
      gload16(W1b + (size_t)(c0 + (j << 4) + b_r) * 512 + k0 + b_ce,        \
              smem + (s) * 24576 + 8192 + (j << 10));                       \
    }                                                                       \
  } while (0)

  STAGE(0, 0);
  __syncthreads();
  for (int t = 0; t < 16; ++t) {
    const int s = t & 1;
    if (t < 15) STAGE(s ^ 1, t + 1);
    const char* Ab = smem + s * 24576;
    const char* Bb = Ab + 8192;
    bf16x8 af[4];
    #pragma unroll
    for (int mi = 0; mi < 4; ++mi) {
      int row = mi*16 + cl;
      const char* base = Ab + row * 128;
      float4 lo = *(const float4*)(base + ((((g<<1)  ) ^ (row & 3)) << 4));
      float4 hi = *(const float4*)(base + ((((g<<1)|1) ^ (row & 3)) << 4));
      af[mi] = pack8f(lo, hi);
    }
    #pragma unroll
    for (int ni = 0; ni < 4; ++ni) {
      bf16x8 bf = *(const bf16x8*)(Bb + (wid*64 + ni*16 + cl) * 64 + g * 16);
      #pragma unroll
      for (int mi = 0; mi < 4; ++mi)
        acc[mi][ni] = __builtin_amdgcn_mfma_f32_16x16x32_bf16(af[mi], bf, acc[mi][ni], 0, 0, 0);
    }
    __syncthreads();
  }
  #undef STAGE

  // epilogue: relu(acc + sproj + b1) * W2, reduce over this wave's 64 cols
  float part[4][4] = {};
  #pragma unroll
  for (int ni = 0; ni < 4; ++ni) {
    int c = c0 + wid*64 + ni*16 + cl;
    float spv = b1[c];
    #pragma unroll
    for (int ks = 0; ks < 4; ++ks)
      spv += sprojp[((size_t)ks*64 + n) * HALFD + c];
    float w2 = W2[c];
    #pragma unroll
    for (int mi = 0; mi < 4; ++mi)
      #pragma unroll
      for (int r = 0; r < 4; ++r)
        part[mi][r] += fmaxf(acc[mi][ni][r] + spv, 0.f) * w2;
  }
  #pragma unroll
  for (int mm = 1; mm < 16; mm <<= 1)
    #pragma unroll
    for (int mi = 0; mi < 4; ++mi)
      #pragma unroll
      for (int r = 0; r < 4; ++r)
        part[mi][r] += __shfl_xor(part[mi][r], mm, 64);
  float* red = (float*)smem;            // [4][64], staging dead
  float* evs = (float*)(smem + 2048);   // [64]
  if (cl == 0) {
    #pragma unroll
    for (int mi = 0; mi < 4; ++mi)
      #pragma unroll
      for (int r = 0; r < 4; ++r)
        red[wid*64 + mi*16 + g*4 + r] = part[mi][r];
  }
  __syncthreads();
  if (tid < 64)
    spart[(size_t)ch * (1024*64) + rt*64 + tid] =
        red[tid] + red[64 + tid] + red[128 + tid] + red[192 + tid];
  __threadfence();
  __syncthreads();
  if (tid == 0) oldLds = atomicAdd(&cnt[rt], 1u);
  __syncthreads();
  if (oldLds == 1u) {     // finisher: partner's scores are visible
    __threadfence();
    if (tid < 64) {
      float s = spart[rt*64 + tid] + spart[1024*64 + rt*64 + tid];
      float M = s;
      #pragma unroll
      for (int mm = 32; mm >= 1; mm >>= 1) M = fmaxf(M, __shfl_xor(M, mm, 64));
      float e = __expf(s - M);
      evs[tid] = e;
      float S = e;
      #pragma unroll
      for (int mm = 32; mm >= 1; mm >>= 1) S += __shfl_xor(S, mm, 64);
      if (tid == 0) { mbuf[rt] = M; sbuf[rt] = S; cnt[rt] = 0u; }
    }
    __syncthreads();
    float2 a2 = {0.f, 0.f};
    const float* ebase = enc + (size_t)r0 * 512 + tid*2;
    #pragma unroll 8
    for (int r = 0; r < 64; ++r) {
      float ev = evs[r];
      float2 x = *(const float2*)(ebase + (size_t)r * 512);
      a2.x = fmaf(ev, x.x, a2.x);
      a2.y = fmaf(ev, x.y, a2.y);
    }
    *(float2*)(ctxp + (size_t)rt * 512 + tid*2) = a2;
  }
}

// ---------- combine 16 tile-partials per n -> context, post concat --------------
__global__ __launch_bounds__(256)
void att_combine(const float* __restrict__ mbuf, const float* __restrict__ sbuf,
                 const float* __restrict__ ctxp, const float* __restrict__ h0out,
                 const float* __restrict__ h1in,
                 float* __restrict__ ctx_out, float* __restrict__ cat)
{
  int i = blockIdx.x * 256 + threadIdx.x;   // < 64*512
  int n = i >> 9, c = i & 511;
  float M = -1e30f;
  #pragma unroll
  for (int b = 0; b < 16; ++b) M = fmaxf(M, mbuf[n*16 + b]);
  float S = 0.f, ctx = 0.f;
  #pragma unroll
  for (int b = 0; b < 16; ++b) {
    float w = __expf(mbuf[n*16 + b] - M);
    S = fmaf(sbuf[n*16 + b], w, S);
    ctx = fmaf(ctxp[(size_t)(n*16 + b)*512 + c], w, ctx);
  }
  ctx /= S;
  ctx_out[i] = ctx;
  cat[(size_t)n * KPOST + c] = h0out[i];
  cat[(size_t)n * KPOST + HSZ + c] = ctx;
  cat[(size_t)n * KPOST + 2*HSZ + c] = h1in[i];
}

// ---------- final softmax over V: z cached in registers (1 read pass) -----------
__global__ __launch_bounds__(1024)
void softmax_v(const float* __restrict__ z, const float* __restrict__ scale,
               const float* __restrict__ shift, float* __restrict__ out)
{
  int n = blockIdx.x, tid = threadIdx.x;
  const float* zr = z + (size_t)n * VSZ;
  float* orow = out + (size_t)n * VSZ;
  __shared__ float rb[16];
  __shared__ float sb[16];
  float v[32]; float mx = -1e30f;
  #pragma unroll
  for (int i = 0; i < 32; ++i) {
    int j = tid + i*1024;
    v[i] = (j < VSZ) ? fmaf(zr[j], scale[j], shift[j]) : -1e30f;
    mx = fmaxf(mx, v[i]);
  }
  #pragma unroll
  for (int m = 32; m >= 1; m >>= 1) mx = fmaxf(mx, __shfl_xor(mx, m, 64));
  if ((tid & 63) == 0) rb[tid >> 6] = mx;
  __syncthreads();
  #pragma unroll
  for (int i = 0; i < 16; ++i) mx = fmaxf(mx, rb[i]);
  float s = 0.f;
  #pragma unroll
  for (int i = 0; i < 32; ++i) { v[i] = __expf(v[i] - mx); s += v[i]; }
  #pragma unroll
  for (int m = 32; m >= 1; m >>= 1) s += __shfl_xor(s, m, 64);
  if ((tid & 63) == 0) sb[tid >> 6] = s;
  __syncthreads();
  s = 0.f;
  #pragma unroll
  for (int i = 0; i < 16; ++i) s += sb[i];
  float inv = 1.0f / s;
  #pragma unroll
  for (int i = 0; i < 32; ++i) {
    int j = tid + i*1024;
    if (j < VSZ) orow[j] = v[i] * inv;
  }
}

// =================================================================================
extern "C" void kernel_launch(void* const* d_in, const int* in_sizes, int n_in,
                              void* d_out, int out_size, void* d_ws, size_t ws_size,
                              hipStream_t stream)
{
  const int*   yt       = (const int*)  d_in[0];
  const float* h0       = (const float*)d_in[1];
  const float* c0       = (const float*)d_in[2];
  const float* h1       = (const float*)d_in[3];
  const float* c1       = (const float*)d_in[4];
  const float* enc      = (const float*)d_in[5];
  const float* c_prev   = (const float*)d_in[6];
  const float* embW     = (const float*)d_in[7];
  const float* pre_Wih  = (const float*)d_in[8];
  const float* pre_Whh  = (const float*)d_in[9];
  const float* pre_bih  = (const float*)d_in[10];
  const float* pre_bhh  = (const float*)d_in[11];
  const float* post_Wih = (const float*)d_in[12];
  const float* post_Whh = (const float*)d_in[13];
  const float* post_bih = (const float*)d_in[14];
  const float* post_bhh = (const float*)d_in[15];
  const float* att_W1   = (const float*)d_in[16];
  const float* att_b1   = (const float*)d_in[17];
  const float* att_W2   = (const float*)d_in[18];
  // d_in[19] = att_b2 cancels under softmax over Tx
  const float* mlp_W    = (const float*)d_in[20];
  const float* mlp_b    = (const float*)d_in[21];
  const float* bn_g     = (const float*)d_in[22];
  const float* bn_b     = (const float*)d_in[23];

  float* out   = (float*)d_out;
  float* o_h0  = out + (size_t)NB * VSZ;
  float* o_c0  = o_h0 + NB * HSZ;
  float* o_h1  = o_c0 + NB * HSZ;
  float* o_c1  = o_h1 + NB * HSZ;
  float* o_ctx = o_c1 + NB * HSZ;

  float* ws = (float*)d_ws;
  // early region (steps 1-6); zbuf (steps 7+) overlays dead early buffers.
  float* pre_cat  = ws;                         // @0          84,736
  float* gatesp   = ws + 84736;                 //             9*131,072 -> 1,264,384
  float* sprojp   = ws + 1264384;               //             131,072   -> 1,395,456
  float* spart    = ws + 1395456;               //             131,072   -> 1,526,528
  float* mbuf     = ws + 1526528;               //             1,024
  float* sbuf     = ws + 1527552;               //             1,024
  unsigned int* cnt = (unsigned int*)(ws + 1528576);  //       1,024     -> 1,529,600
  float* ctxp     = ws + 1529600;               //             524,288   -> 2,053,888
  float* post_cat = ws + 2053888;               //             98,304    -> 2,152,192
  unsigned short* W1b = (unsigned short*)(ws + 2152192);  //   262,144 u16 -> 2,283,264
  float* zbuf     = ws;                         // @0 overlay, 2,048,000 (cnt clobbered; prep re-zeroes)
  float* bnsc     = ws + 2283264;               //             32,000
  float* bnsh     = ws + 2315264;               //             32,000 -> 2,347,264 f (9.39 MB)

  // 1. prep: W1->bf16, pre concat, zero pair-counters
  prep<<<461, 256, 0, stream>>>(yt, embW, c_prev, h0, att_W1, W1b, pre_cat, cnt);
  // 2. pre gates (fused ih+hh, split-K x9) + LSTM pointwise
  mfma_gemm128<0><<<dim3(G4/128, 9), 256, 0, stream>>>(
      pre_cat, KPRE, KPRE, pre_Wih, ESZ + NHD, ESZ + NHD, pre_Whh, HSZ,
      nullptr, gatesp, G4, 160, nullptr, nullptr, nullptr, nullptr);
  lstm_point2<<<NB*HSZ/256, 256, 0, stream>>>(gatesp, 9, pre_bih, pre_bhh, c0, o_h0, o_c0);
  // 3. sproj partials: s_i @ W1_s^T (split-K x4)
  mfma_gemm128<0><<<dim3(HALFD/128, 4), 256, 0, stream>>>(
      o_h0, HSZ, HSZ, att_W1 + NHD, NHD + HSZ, HSZ, att_W1 + NHD, NHD + HSZ,
      nullptr, sprojp, HALFD, 128, nullptr, nullptr, nullptr, nullptr);
  // 4. fused attention (scores + pair softmax + context partials) + combine
  att_fused2<<<2048, 256, 0, stream>>>(enc, W1b, att_W2, sprojp, att_b1,
                                       spart, mbuf, sbuf, ctxp, cnt);
  att_combine<<<NB*NHD/256, 256, 0, stream>>>(mbuf, sbuf, ctxp, o_h0, h1, o_ctx, post_cat);
  // 5. post gates (fused ih+hh, split-K x8) + LSTM pointwise
  mfma_gemm128<0><<<dim3(G4/128, 8), 256, 0, stream>>>(
      post_cat, KPOST, KPOST, post_Wih, HSZ + NHD, HSZ + NHD, post_Whh, HSZ,
      nullptr, gatesp, G4, 192, nullptr, nullptr, nullptr, nullptr);
  lstm_point2<<<NB*HSZ/256, 256, 0, stream>>>(gatesp, 8, post_bih, post_bhh, c1, o_h1, o_c1);
  // 6. classifier z = relu(h1 @ mlp_W^T + b) with fused BN-stats epilogue
  mfma_gemm128<4><<<dim3(VSZ/128, 1), 256, 0, stream>>>(
      o_h1, HSZ, HSZ, mlp_W, HSZ, HSZ, mlp_W, HSZ, mlp_b, zbuf, VSZ, 512,
      bn_g, bn_b, bnsc, bnsh);
  // 7. softmax over V (BN applied on the fly)
  softmax_v<<<NB, 1024, 0, stream>>>(zbuf, bnsc, bnsh, out);
}

// Round 7
// 170.876 us; speedup vs baseline: 3.3302x; 3.3302x over previous
//
#include <hip/hip_runtime.h>
#include <math.h>

#define DEVFN __device__ __forceinline__

typedef __attribute__((ext_vector_type(4))) float f32x4;
typedef __attribute__((ext_vector_type(8))) __bf16 bf16x8;
typedef __attribute__((ext_vector_type(8))) short short8v;

#define NB   64
#define TXD  1024
#define NHD  512
#define HSZ  512
#define ESZ  300
#define VSZ  32000
#define G4   (4*HSZ)           // 2048
#define KPRE (ESZ + NHD + HSZ) // 1324 (emb|c_prev|h0)
#define KPOST 1536             // (h0out|ctx|h1)
#define HALFD 512

DEVFN short f2bf(float f) {
  unsigned u = __float_as_uint(f);
  u = (u + 0x7fffu + ((u >> 16) & 1u)) >> 16;
  return (short)u;
}
DEVFN float sigm(float x) { return 1.0f / (1.0f + __expf(-x)); }

DEVFN short8v pack8(float4 a, float4 b) {
  short8v v;
  v[0]=f2bf(a.x); v[1]=f2bf(a.y); v[2]=f2bf(a.z); v[3]=f2bf(a.w);
  v[4]=f2bf(b.x); v[5]=f2bf(b.y); v[6]=f2bf(b.z); v[7]=f2bf(b.w);
  return v;
}
// async global->LDS, 16B per lane: dest = wave-uniform base + lane*16
DEVFN void gload16(const void* g, void* lds_base) {
  __builtin_amdgcn_global_load_lds(
      (const __attribute__((address_space(1))) unsigned int*)g,
      (__attribute__((address_space(3))) unsigned int*)lds_base, 16, 0, 0);
}

DEVFN float4 ldA4(const float* __restrict__ A, int lda, int row, int k, int Ka) {
  if (k >= Ka) { float4 z = {0.f,0.f,0.f,0.f}; return z; }
  return *(const float4*)(A + (size_t)row * lda + k);
}
DEVFN float4 ldB4(const float* __restrict__ B1, int ldb1, int split,
                  const float* __restrict__ B2, int ldb2, int row, int k, int Ka) {
  if (k >= Ka) { float4 z = {0.f,0.f,0.f,0.f}; return z; }
  if (k < split) return *(const float4*)(B1 + (size_t)row * ldb1 + k);
  return *(const float4*)(B2 + (size_t)row * ldb2 + (k - split));
}

// ---------- prep: W1->bf16 (blocks 0..127) | pre concat (128..458) --------------
__global__ __launch_bounds__(256)
void prep(const int* __restrict__ yt, const float* __restrict__ embW,
          const float* __restrict__ c_prev, const float* __restrict__ h0,
          const float* __restrict__ W1, unsigned short* __restrict__ W1b,
          float* __restrict__ cat)
{
  int b = blockIdx.x;
  if (b < 128) {
    int i = b * 256 + threadIdx.x;            // 0..32767, 8 elems each
    int c = i >> 6, kq = (i & 63) * 8;
    float4 a = *(const float4*)(W1 + (size_t)c * 1024 + kq);
    float4 bb = *(const float4*)(W1 + (size_t)c * 1024 + kq + 4);
    *(short8v*)(W1b + (size_t)c * 512 + kq) = pack8(a, bb);
  } else {
    int i = (b - 128) * 256 + threadIdx.x;    // < 64*1324
    if (i >= NB * KPRE) return;
    int n = i / KPRE, c = i - n * KPRE;
    float v;
    if (c < ESZ)            v = embW[(size_t)yt[n] * ESZ + c];
    else if (c < ESZ + NHD) v = c_prev[(size_t)n * NHD + (c - ESZ)];
    else                    v = h0[(size_t)n * HSZ + (c - ESZ - NHD)];
    cat[i] = v;
  }
}

// ---------- generic MFMA GEMM, 128-col tiles: C[64 x N] = A[64 x K] B[N x K]^T --
// Kslice multiple of 32. Split-K partial at C + ks*64*ldc.
// EPI: 0 none, 4 relu(x+bias1) + fused BN scale/shift outputs.
template<int EPI>
__global__ __launch_bounds__(256)
void mfma_gemm128(const float* __restrict__ A, int lda, int Ka,
                  const float* __restrict__ B1, int ldb1, int split,
                  const float* __restrict__ B2, int ldb2,
                  const float* __restrict__ bias1,
                  float* __restrict__ C, int ldc, int Kslice,
                  const float* __restrict__ gamma, const float* __restrict__ beta,
                  float* __restrict__ bnsc, float* __restrict__ bnsh)
{
  __shared__ __align__(16) short As[64][40];
  __shared__ __align__(16) short Bs[128][40];
  const int tid = threadIdx.x;
  const int w = tid >> 6, lane = tid & 63;
  const int wr = w >> 1, wc = w & 1;
  const int cl = lane & 15, g = lane >> 4;
  const int n0 = blockIdx.x * 128;
  const int ks = blockIdx.y;
  const int kbeg = ks * Kslice;
  const int kend = min(kbeg + Kslice, Ka);
  C += (size_t)ks * 64 * ldc;

  const f32x4 fz = {0.f,0.f,0.f,0.f};
  f32x4 acc[2][4];
  #pragma unroll
  for (int i = 0; i < 2; ++i)
    #pragma unroll
    for (int j = 0; j < 4; ++j) acc[i][j] = fz;

  const int sr  = tid >> 2;        // 0..63
  const int skc = (tid & 3) * 8;   // 0,8,16,24

  float4 ra0, ra1, rb0[2], rb1[2];
  ra0 = ldA4(A, lda, sr, kbeg + skc, Ka);
  ra1 = ldA4(A, lda, sr, kbeg + skc + 4, Ka);
  #pragma unroll
  for (int it = 0; it < 2; ++it) {
    rb0[it] = ldB4(B1, ldb1, split, B2, ldb2, n0 + sr + it*64, kbeg + skc, Ka);
    rb1[it] = ldB4(B1, ldb1, split, B2, ldb2, n0 + sr + it*64, kbeg + skc + 4, Ka);
  }

  for (int k0 = kbeg; k0 < kend; k0 += 32) {
    __syncthreads();
    *(short8v*)&As[sr][skc] = pack8(ra0, ra1);
    #pragma unroll
    for (int it = 0; it < 2; ++it)
      *(short8v*)&Bs[sr + it*64][skc] = pack8(rb0[it], rb1[it]);
    __syncthreads();
    if (k0 + 32 < kend) {
      ra0 = ldA4(A, lda, sr, k0 + 32 + skc, Ka);
      ra1 = ldA4(A, lda, sr, k0 + 32 + skc + 4, Ka);
      #pragma unroll
      for (int it = 0; it < 2; ++it) {
        rb0[it] = ldB4(B1, ldb1, split, B2, ldb2, n0 + sr + it*64, k0 + 32 + skc, Ka);
        rb1[it] = ldB4(B1, ldb1, split, B2, ldb2, n0 + sr + it*64, k0 + 32 + skc + 4, Ka);
      }
    }
    bf16x8 af[2], bfr[4];
    #pragma unroll
    for (int mi = 0; mi < 2; ++mi)
      af[mi] = *(const bf16x8*)&As[wr*32 + mi*16 + cl][g * 8];
    #pragma unroll
    for (int ni = 0; ni < 4; ++ni)
      bfr[ni] = *(const bf16x8*)&Bs[wc*64 + ni*16 + cl][g * 8];
    #pragma unroll
    for (int mi = 0; mi < 2; ++mi)
      #pragma unroll
      for (int ni = 0; ni < 4; ++ni)
        acc[mi][ni] = __builtin_amdgcn_mfma_f32_16x16x32_bf16(af[mi], bfr[ni], acc[mi][ni], 0, 0, 0);
  }

  float s1[4] = {0.f,0.f,0.f,0.f}, s2[4] = {0.f,0.f,0.f,0.f};
  #pragma unroll
  for (int ni = 0; ni < 4; ++ni) {
    int nn = n0 + wc*64 + ni*16 + cl;
    float b = (EPI == 4) ? bias1[nn] : 0.f;
    #pragma unroll
    for (int mi = 0; mi < 2; ++mi)
      #pragma unroll
      for (int r = 0; r < 4; ++r) {
        int m = wr*32 + mi*16 + g*4 + r;
        float v = acc[mi][ni][r];
        if (EPI == 4) v = fmaxf(v + b, 0.f);
        C[(size_t)m * ldc + nn] = v;
        if (EPI == 4) { s1[ni] += v; s2[ni] = fmaf(v, v, s2[ni]); }
      }
  }
  if (EPI == 4) {
    #pragma unroll
    for (int mm = 16; mm < 64; mm <<= 1)
      #pragma unroll
      for (int ni = 0; ni < 4; ++ni) {
        s1[ni] += __shfl_xor(s1[ni], mm, 64);
        s2[ni] += __shfl_xor(s2[ni], mm, 64);
      }
    float* red = (float*)As;   // 2KB, staging dead
    __syncthreads();
    if (g == 0) {
      #pragma unroll
      for (int ni = 0; ni < 4; ++ni) {
        int col = wc*64 + ni*16 + cl;
        red[(wr*128 + col)*2 + 0] = s1[ni];
        red[(wr*128 + col)*2 + 1] = s2[ni];
      }
    }
    __syncthreads();
    if (tid < 128) {
      int col = n0 + tid;
      float a1 = red[tid*2] + red[(128 + tid)*2];
      float a2 = red[tid*2 + 1] + red[(128 + tid)*2 + 1];
      float mean = a1 * (1.0f / NB);
      float var = a2 * (1.0f / NB) - mean * mean;
      float rr = rsqrtf(var + 1e-5f);
      float sc = gamma[col] * rr;
      bnsc[col] = sc;
      bnsh[col] = beta[col] - mean * sc;
    }
  }
}

// ---------- LSTM pointwise, summing np split-K gate partials --------------------
__global__ __launch_bounds__(256)
void lstm_point2(const float* __restrict__ gp, int np,
                 const float* __restrict__ bih, const float* __restrict__ bhh,
                 const float* __restrict__ c_old,
                 float* __restrict__ h_new, float* __restrict__ c_new)
{
  int i = blockIdx.x * 256 + threadIdx.x;   // < 64*512
  int n = i >> 9, k = i & 511;
  float g[4];
  #pragma unroll
  for (int j = 0; j < 4; ++j) {
    int idx = j * 512 + k;
    float s = bih[idx] + bhh[idx];
    for (int ks = 0; ks < np; ++ks)
      s += gp[((size_t)ks*64 + n) * G4 + idx];
    g[j] = s;
  }
  float c = sigm(g[1]) * c_old[i] + sigm(g[0]) * tanhf(g[2]);
  float h = sigm(g[3]) * tanhf(c);
  h_new[i] = h; c_new[i] = c;
}

// ---------- attention scores: 64 rows x 256 cols, counted-vmcnt 2-stage ---------
// grid 2048 = 1024 row-tiles x 2 col-halves. 4 waves; wave tile 64x64, acc 4x4.
// Both tiles bf16 in LDS, layout: line = row>>1 (128B), half = row&1,
// slot16 = g ^ (line&3). A reg-staged (f32->bf16), B via global_load_lds.
// Per-wave VMEM per step: A 2 loads, B 4 gloads -> vmcnt(4)=A-arrived,
// vmcnt(2)=B-done. Raw s_barrier, never drain mid-loop.
__global__ __launch_bounds__(256)
void att_score(const float* __restrict__ enc, const unsigned short* __restrict__ W1b,
               const float* __restrict__ W2, const float* __restrict__ sprojp,
               const float* __restrict__ b1, float* __restrict__ spart)
{
  __shared__ __align__(16) char smem[40960];  // A 2x4KB @0, B 2x16KB @8192
  const int tid = threadIdx.x;
  const int wid = tid >> 6, lane = tid & 63;
  const int cl = lane & 15, g = lane >> 4;
  const int rt = blockIdx.x >> 1, ch = blockIdx.x & 1;
  const int r0 = rt << 6;
  const int c0 = ch << 8;
  const int n  = rt >> 4;

  // A chunk decode (chunk = tid, 16B dest at tid*16)
  const int a_row = ((tid >> 3) << 1) + ((tid >> 2) & 1);    // 0..63
  const int a_qf  = (((tid & 3) ^ ((tid >> 3) & 3)) << 3);   // f32 units
  // B gload lane decode
  const int b_r = ((lane >> 3) << 1) + ((lane >> 2) & 1);    // 0..15
  const int b_q = (((lane & 3) ^ ((lane >> 3) & 3)) << 3);   // bf16 units

  const f32x4 fz = {0.f,0.f,0.f,0.f};
  f32x4 acc[4][4];
  #pragma unroll
  for (int mi = 0; mi < 4; ++mi)
    #pragma unroll
    for (int ni = 0; ni < 4; ++ni) acc[mi][ni] = fz;

  float4 a_lo, a_hi;
  #define A_LOAD(tt) do { \
    const float* asrc = enc + (size_t)(r0 + a_row) * 512 + (tt) * 32 + a_qf; \
    a_lo = *(const float4*)asrc; a_hi = *(const float4*)(asrc + 4); } while (0)
  #define A_WRITE(buf) \
    *(short8v*)(smem + (buf) * 4096 + tid * 16) = pack8(a_lo, a_hi)
  #define STAGE_B(buf, tt) do { int k0 = (tt) * 32; \
    _Pragma("unroll") \
    for (int jj = 0; jj < 4; ++jj) { int j = (wid << 2) + jj; \
      gload16(W1b + (size_t)(c0 + (j << 4) + b_r) * 512 + k0 + b_q, \
              smem + 8192 + (buf) * 16384 + (j << 10)); } } while (0)

  // prologue
  A_LOAD(0);                 // out: A2
  STAGE_B(0, 0);             // out: A2 + B4
  asm volatile("s_waitcnt vmcnt(4)" ::: "memory");   // A(0) arrived
  A_WRITE(0);
  A_LOAD(1);                 // out: B4 + A2
  asm volatile("s_waitcnt vmcnt(2)" ::: "memory");   // B(0) done
  asm volatile("s_waitcnt lgkmcnt(0)" ::: "memory");
  __builtin_amdgcn_s_barrier();
  __builtin_amdgcn_sched_barrier(0);

  for (int t = 0; t < 16; ++t) {
    const int s = t & 1;
    if (t < 15) {
      STAGE_B(s ^ 1, t + 1);                          // out: A2(old)+B4
      asm volatile("s_waitcnt vmcnt(4)" ::: "memory"); // A(t+1) arrived
      A_WRITE(s ^ 1);
      if (t < 14) A_LOAD(t + 2);                       // out: B4+A2
    }
    const char* Ab = smem + s * 4096;
    const char* Bb = smem + 8192 + s * 16384;
    bf16x8 af[4];
    #pragma unroll
    for (int mi = 0; mi < 4; ++mi) {
      int r = mi * 16 + cl;
      af[mi] = *(const bf16x8*)(Ab + (r >> 1) * 128 + (r & 1) * 64
                                + ((g ^ ((r >> 1) & 3)) << 4));
    }
    #pragma unroll
    for (int ni = 0; ni < 4; ++ni) {
      int r = wid * 64 + ni * 16 + cl;
      bf16x8 bf = *(const bf16x8*)(Bb + (r >> 1) * 128 + (r & 1) * 64
                                   + ((g ^ ((r >> 1) & 3)) << 4));
      #pragma unroll
      for (int mi = 0; mi < 4; ++mi)
        acc[mi][ni] = __builtin_amdgcn_mfma_f32_16x16x32_bf16(af[mi], bf, acc[mi][ni], 0, 0, 0);
    }
    if (t < 15) {
      if (t < 14) asm volatile("s_waitcnt vmcnt(2)" ::: "memory");  // B(t+1) done
      else        asm volatile("s_waitcnt vmcnt(0)" ::: "memory");
      asm volatile("s_waitcnt lgkmcnt(0)" ::: "memory");
      __builtin_amdgcn_s_barrier();
      __builtin_amdgcn_sched_barrier(0);
    }
  }
  #undef A_LOAD
  #undef A_WRITE
  #undef STAGE_B
  __syncthreads();

  // epilogue: relu(acc + sproj + b1) * W2, reduce over this wave's 64 cols
  float part[4][4] = {};
  #pragma unroll
  for (int ni = 0; ni < 4; ++ni) {
    int c = c0 + wid*64 + ni*16 + cl;
    float spv = b1[c];
    #pragma unroll
    for (int ks = 0; ks < 4; ++ks)
      spv += sprojp[((size_t)ks*64 + n) * HALFD + c];
    float w2 = W2[c];
    #pragma unroll
    for (int mi = 0; mi < 4; ++mi)
      #pragma unroll
      for (int r = 0; r < 4; ++r)
        part[mi][r] += fmaxf(acc[mi][ni][r] + spv, 0.f) * w2;
  }
  #pragma unroll
  for (int mm = 1; mm < 16; mm <<= 1)
    #pragma unroll
    for (int mi = 0; mi < 4; ++mi)
      #pragma unroll
      for (int r = 0; r < 4; ++r)
        part[mi][r] += __shfl_xor(part[mi][r], mm, 64);
  float* red = (float*)smem;   // [4][64], staging dead
  if (cl == 0) {
    #pragma unroll
    for (int mi = 0; mi < 4; ++mi)
      #pragma unroll
      for (int r = 0; r < 4; ++r)
        red[wid*64 + mi*16 + g*4 + r] = part[mi][r];
  }
  __syncthreads();
  if (tid < 64)
    spart[(size_t)ch * (NB*TXD) + r0 + tid] =
        red[tid] + red[64 + tid] + red[128 + tid] + red[192 + tid];
}

// ---------- softmax over Tx -> alphas [64, 1024] (2 col-half parts) -------------
__global__ __launch_bounds__(256)
void softmax_tx(const float* __restrict__ spart, float* __restrict__ alphas)
{
  int n = blockIdx.x, tid = threadIdx.x;
  __shared__ float rb[4];
  __shared__ float sb[4];
  float v[4]; float mx = -1e30f;
  #pragma unroll
  for (int i = 0; i < 4; ++i) {
    int t = tid + i*256;
    v[i] = spart[(size_t)n*TXD + t] + spart[(size_t)NB*TXD + (size_t)n*TXD + t];
    mx = fmaxf(mx, v[i]);
  }
  #pragma unroll
  for (int m = 32; m >= 1; m >>= 1) mx = fmaxf(mx, __shfl_xor(mx, m, 64));
  if ((tid & 63) == 0) rb[tid >> 6] = mx;
  __syncthreads();
  mx = fmaxf(fmaxf(rb[0], rb[1]), fmaxf(rb[2], rb[3]));
  float s = 0.f;
  #pragma unroll
  for (int i = 0; i < 4; ++i) { v[i] = __expf(v[i] - mx); s += v[i]; }
  #pragma unroll
  for (int m = 32; m >= 1; m >>= 1) s += __shfl_xor(s, m, 64);
  if ((tid & 63) == 0) sb[tid >> 6] = s;
  __syncthreads();
  s = sb[0] + sb[1] + sb[2] + sb[3];
  float inv = 1.0f / s;
  #pragma unroll
  for (int i = 0; i < 4; ++i) alphas[(size_t)n*TXD + tid + i*256] = v[i] * inv;
}

// ---------- context partial sums (8 chunks of 128 timesteps) --------------------
__global__ __launch_bounds__(512)
void context_partial(const float* __restrict__ enc, const float* __restrict__ alphas,
                     float* __restrict__ part)
{
  int n = blockIdx.y, chunk = blockIdx.x;
  int c = threadIdx.x;
  __shared__ float al[128];
  if (threadIdx.x < 128) al[threadIdx.x] = alphas[(size_t)n*TXD + chunk*128 + threadIdx.x];
  __syncthreads();
  const float* e = enc + ((size_t)n*TXD + chunk*128) * NHD + c;
  float s = 0.f;
  #pragma unroll 4
  for (int t = 0; t < 128; ++t) s = fmaf(al[t], e[(size_t)t * NHD], s);
  part[((size_t)n*8 + chunk) * NHD + c] = s;
}

// ---------- reduce context + build post concat [h0out | ctx | h1] ---------------
__global__ __launch_bounds__(256)
void finalize_context(const float* __restrict__ part, const float* __restrict__ h0out,
                      const float* __restrict__ h1in,
                      float* __restrict__ ctx_out, float* __restrict__ cat)
{
  int i = blockIdx.x * 256 + threadIdx.x;   // < 64*512
  int n = i >> 9, c = i & 511;
  float s = 0.f;
  #pragma unroll
  for (int j = 0; j < 8; ++j) s += part[((size_t)n*8 + j) * NHD + c];
  ctx_out[i] = s;
  cat[(size_t)n * KPOST + c] = h0out[i];
  cat[(size_t)n * KPOST + HSZ + c] = s;
  cat[(size_t)n * KPOST + 2*HSZ + c] = h1in[i];
}

// ---------- final softmax over V: z cached in registers (1 read pass) -----------
__global__ __launch_bounds__(1024)
void softmax_v(const float* __restrict__ z, const float* __restrict__ scale,
               const float* __restrict__ shift, float* __restrict__ out)
{
  int n = blockIdx.x, tid = threadIdx.x;
  const float* zr = z + (size_t)n * VSZ;
  float* orow = out + (size_t)n * VSZ;
  __shared__ float rb[16];
  __shared__ float sb[16];
  float v[32]; float mx = -1e30f;
  #pragma unroll
  for (int i = 0; i < 32; ++i) {
    int j = tid + i*1024;
    v[i] = (j < VSZ) ? fmaf(zr[j], scale[j], shift[j]) : -1e30f;
    mx = fmaxf(mx, v[i]);
  }
  #pragma unroll
  for (int m = 32; m >= 1; m >>= 1) mx = fmaxf(mx, __shfl_xor(mx, m, 64));
  if ((tid & 63) == 0) rb[tid >> 6] = mx;
  __syncthreads();
  #pragma unroll
  for (int i = 0; i < 16; ++i) mx = fmaxf(mx, rb[i]);
  float s = 0.f;
  #pragma unroll
  for (int i = 0; i < 32; ++i) { v[i] = __expf(v[i] - mx); s += v[i]; }
  #pragma unroll
  for (int m = 32; m >= 1; m >>= 1) s += __shfl_xor(s, m, 64);
  if ((tid & 63) == 0) sb[tid >> 6] = s;
  __syncthreads();
  s = 0.f;
  #pragma unroll
  for (int i = 0; i < 16; ++i) s += sb[i];
  float inv = 1.0f / s;
  #pragma unroll
  for (int i = 0; i < 32; ++i) {
    int j = tid + i*1024;
    if (j < VSZ) orow[j] = v[i] * inv;
  }
}

// =================================================================================
extern "C" void kernel_launch(void* const* d_in, const int* in_sizes, int n_in,
                              void* d_out, int out_size, void* d_ws, size_t ws_size,
                              hipStream_t stream)
{
  const int*   yt       = (const int*)  d_in[0];
  const float* h0       = (const float*)d_in[1];
  const float* c0       = (const float*)d_in[2];
  const float* h1       = (const float*)d_in[3];
  const float* c1       = (const float*)d_in[4];
  const float* enc      = (const float*)d_in[5];
  const float* c_prev   = (const float*)d_in[6];
  const float* embW     = (const float*)d_in[7];
  const float* pre_Wih  = (const float*)d_in[8];
  const float* pre_Whh  = (const float*)d_in[9];
  const float* pre_bih  = (const float*)d_in[10];
  const float* pre_bhh  = (const float*)d_in[11];
  const float* post_Wih = (const float*)d_in[12];
  const float* post_Whh = (const float*)d_in[13];
  const float* post_bih = (const float*)d_in[14];
  const float* post_bhh = (const float*)d_in[15];
  const float* att_W1   = (const float*)d_in[16];
  const float* att_b1   = (const float*)d_in[17];
  const float* att_W2   = (const float*)d_in[18];
  // d_in[19] = att_b2 cancels under softmax over Tx
  const float* mlp_W    = (const float*)d_in[20];
  const float* mlp_b    = (const float*)d_in[21];
  const float* bn_g     = (const float*)d_in[22];
  const float* bn_b     = (const float*)d_in[23];

  float* out   = (float*)d_out;
  float* o_h0  = out + (size_t)NB * VSZ;
  float* o_c0  = o_h0 + NB * HSZ;
  float* o_h1  = o_c0 + NB * HSZ;
  float* o_c1  = o_h1 + NB * HSZ;
  float* o_ctx = o_c1 + NB * HSZ;

  float* ws = (float*)d_ws;
  // early region (steps 1-6); zbuf (steps 7+) overlays dead early buffers.
  float* pre_cat  = ws;                         // @0          84,736
  float* gatesp   = ws + 84736;                 //             9*131,072 -> 1,264,384
  float* sprojp   = ws + 1264384;               //             131,072   -> 1,395,456
  float* spart    = ws + 1395456;               //             131,072   -> 1,526,528
  float* alphas   = ws + 1526528;               //             65,536    -> 1,592,064
  float* ctxp     = ws + 1592064;               //             262,144   -> 1,854,208
  float* post_cat = ws + 1854208;               //             98,304    -> 1,952,512
  unsigned short* W1b = (unsigned short*)(ws + 1952512);  //   262,144 u16 -> 2,083,584
  float* zbuf     = ws;                         // @0 overlay, 2,048,000 (step 6+)
  float* bnsc     = ws + 2083584;               //             32,000
  float* bnsh     = ws + 2115584;               //             32,000 -> 2,147,584 f (8.59 MB)

  // 1. prep: W1->bf16 + pre concat [emb | c_prev | h0]
  prep<<<459, 256, 0, stream>>>(yt, embW, c_prev, h0, att_W1, W1b, pre_cat);
  // 2. pre gates (fused ih+hh, split-K x9) + LSTM pointwise
  mfma_gemm128<0><<<dim3(G4/128, 9), 256, 0, stream>>>(
      pre_cat, KPRE, KPRE, pre_Wih, ESZ + NHD, ESZ + NHD, pre_Whh, HSZ,
      nullptr, gatesp, G4, 160, nullptr, nullptr, nullptr, nullptr);
  lstm_point2<<<NB*HSZ/256, 256, 0, stream>>>(gatesp, 9, pre_bih, pre_bhh, c0, o_h0, o_c0);
  // 3. sproj partials: s_i @ W1_s^T (split-K x4)
  mfma_gemm128<0><<<dim3(HALFD/128, 4), 256, 0, stream>>>(
      o_h0, HSZ, HSZ, att_W1 + NHD, NHD + HSZ, HSZ, att_W1 + NHD, NHD + HSZ,
      nullptr, sprojp, HALFD, 128, nullptr, nullptr, nullptr, nullptr);
  // 4. attention scores (counted-vmcnt pipeline) + softmax + context
  att_score<<<2048, 256, 0, stream>>>(enc, W1b, att_W2, sprojp, att_b1, spart);
  softmax_tx<<<NB, 256, 0, stream>>>(spart, alphas);
  context_partial<<<dim3(8, NB), 512, 0, stream>>>(enc, alphas, ctxp);
  finalize_context<<<NB*NHD/256, 256, 0, stream>>>(ctxp, o_h0, h1, o_ctx, post_cat);
  // 5. post gates (fused ih+hh, split-K x8) + LSTM pointwise
  mfma_gemm128<0><<<dim3(G4/128, 8), 256, 0, stream>>>(
      post_cat, KPOST, KPOST, post_Wih, HSZ + NHD, HSZ + NHD, post_Whh, HSZ,
      nullptr, gatesp, G4, 192, nullptr, nullptr, nullptr, nullptr);
  lstm_point2<<<NB*HSZ/256, 256, 0, stream>>>(gatesp, 8, post_bih, post_bhh, c1, o_h1, o_c1);
  // 6. classifier z = relu(h1 @ mlp_W^T + b) with fused BN-stats epilogue
  mfma_gemm128<4><<<dim3(VSZ/128, 1), 256, 0, stream>>>(
      o_h1, HSZ, HSZ, mlp_W, HSZ, HSZ, mlp_W, HSZ, mlp_b, zbuf, VSZ, 512,
      bn_g, bn_b, bnsc, bnsh);
  // 7. softmax over V (BN applied on the fly)
  softmax_v<<<NB, 1024, 0, stream>>>(zbuf, bnsc, bnsh, out);
}